// Round 12
// baseline (138.722 us; speedup 1.0000x reference)
//
#include <hip/hip_runtime.h>
#include <stdint.h>

// Problem constants
#define BB 16
#define TT 4096
#define HH 64
#define MM 640    // HH*DD

// ---------------------------------------------------------------------------
// Kernel 1: ksum[b][m] = sum_t key[b][t][m]  (~27 us, near read roofline)
// ---------------------------------------------------------------------------
__global__ void __launch_bounds__(256)
ksum_kernel(const float* __restrict__ key, float* __restrict__ ksum) {
    int g = blockIdx.x * blockDim.x + threadIdx.x;   // b*160 + c
    int b = g / 160;
    int c = g % 160;
    int t0 = blockIdx.y * 32;

    const float4* p = reinterpret_cast<const float4*>(key)
                    + (size_t)b * TT * 160 + (size_t)t0 * 160 + c;

    float4 a0 = make_float4(0.f,0.f,0.f,0.f);
    float4 a1 = make_float4(0.f,0.f,0.f,0.f);
    float4 a2 = make_float4(0.f,0.f,0.f,0.f);
    float4 a3 = make_float4(0.f,0.f,0.f,0.f);
    #pragma unroll
    for (int i = 0; i < 32; i += 4) {
        float4 x0 = p[(size_t)(i + 0) * 160];
        float4 x1 = p[(size_t)(i + 1) * 160];
        float4 x2 = p[(size_t)(i + 2) * 160];
        float4 x3 = p[(size_t)(i + 3) * 160];
        a0.x += x0.x; a0.y += x0.y; a0.z += x0.z; a0.w += x0.w;
        a1.x += x1.x; a1.y += x1.y; a1.z += x1.z; a1.w += x1.w;
        a2.x += x2.x; a2.y += x2.y; a2.z += x2.z; a2.w += x2.w;
        a3.x += x3.x; a3.y += x3.y; a3.z += x3.z; a3.w += x3.w;
    }
    float sx = (a0.x + a1.x) + (a2.x + a3.x);
    float sy = (a0.y + a1.y) + (a2.y + a3.y);
    float sz = (a0.z + a1.z) + (a2.z + a3.z);
    float sw = (a0.w + a1.w) + (a2.w + a3.w);

    float* dst = ksum + b * MM + c * 4;
    atomicAdd(dst + 0, sx);
    atomicAdd(dst + 1, sy);
    atomicAdd(dst + 2, sz);
    atomicAdd(dst + 3, sw);
}

// ---------------------------------------------------------------------------
// Robust tanh via rcp (exp of negative arg only -> never overflows)
// ---------------------------------------------------------------------------
__device__ __forceinline__ float tanh_rcp(float x) {
    float ax = fabsf(x);
    float e2 = __expf(-2.0f * ax);
    float th = (1.0f - e2) * __builtin_amdgcn_rcpf(1.0f + e2);
    return copysignf(th, x);
}

// ---------------------------------------------------------------------------
// Kernel 2: pure streaming, NO mid-stream drain.
//   - ksum: ONE f4/thread (tid<160) -> LDS; barrier BEFORE any streaming
//     load is issued (drain costs one L2-hot load, not the stream).
//   - q/v: thread = (b, t, head-pair); 20 floats = 5 aligned f4 per tensor,
//     issued interleaved, consumed from regs via compiler-COUNTED vmcnt --
//     no barrier after, no vmcnt(0), block exits. Waves desynchronize ->
//     memory always busy (the ksum_kernel property, 6+ TB/s regime).
//   - stores: 2 floats, 16KB apart; L2 merges siblings (R10: 17.9 MB, ok).
// ---------------------------------------------------------------------------
__global__ void __launch_bounds__(256)
attn_kernel(const float* __restrict__ q,
            const float* __restrict__ v,
            const float* __restrict__ ksum,
            float* __restrict__ out) {
    __shared__ float ks_lds[MM];                     // 2.56 KB

    const int tid = threadIdx.x;
    const int u   = blockIdx.x * 256 + tid;          // unit index
    const int hp  = u & 31;                          // head pair 0..31
    const int t   = (u >> 5) & (TT - 1);
    const int b   = u >> 17;                         // block-uniform

    // ---- stage ksum slice (block-uniform b) before streaming starts ----
    if (tid < 160) {
        reinterpret_cast<float4*>(ks_lds)[tid] =
            reinterpret_cast<const float4*>(ksum + (size_t)b * MM)[tid];
    }
    __syncthreads();

    // ---- issue the 10 streaming loads, interleaved q/v ----
    const float4* qp = reinterpret_cast<const float4*>(
        q + ((size_t)b * TT + t) * MM + hp * 20);
    const float4* vp = reinterpret_cast<const float4*>(
        v + ((size_t)b * TT + t) * MM + hp * 20);

    float4 rq[5], rv[5];
    #pragma unroll
    for (int j = 0; j < 5; ++j) {
        rq[j] = qp[j];
        rv[j] = vp[j];
    }

    // ---- ksr from LDS (one-time, conflicts amortized) ----
    const float R = 0.316227766016838f;              // 1/sqrt(10)
    float ksr[20];
    #pragma unroll
    for (int j = 0; j < 20; ++j) ksr[j] = ks_lds[hp * 20 + j] * R;

    const float* qf = reinterpret_cast<const float*>(rq);
    const float* vf = reinterpret_cast<const float*>(rv);

    float res[2];
    #pragma unroll
    for (int h = 0; h < 2; ++h) {
        float sum = 0.f, dot = 0.f;
        #pragma unroll
        for (int d = 0; d < 10; ++d) {
            int j = h * 10 + d;                      // compile-time constant
            float e = __expf(tanh_rcp(qf[j] * ksr[j]));
            sum += e;
            dot += e * vf[j];
        }
        res[h] = dot * __builtin_amdgcn_rcpf(sum);
    }

    float* ob = out + ((size_t)(b * HH + hp * 2)) * TT + t;
    ob[0]  = res[0];
    ob[TT] = res[1];
}

// ---------------------------------------------------------------------------
extern "C" void kernel_launch(void* const* d_in, const int* in_sizes, int n_in,
                              void* d_out, int out_size, void* d_ws, size_t ws_size,
                              hipStream_t stream) {
    const float* q = (const float*)d_in[0];
    const float* k = (const float*)d_in[1];
    const float* v = (const float*)d_in[2];
    // d_in[3] = W, d_in[4] = b : dead code (softmax over size-1 axis == 1)
    float* out  = (float*)d_out;
    float* ksum = (float*)d_ws;    // B*M floats = 40 KB

    hipMemsetAsync(d_ws, 0, (size_t)BB * MM * sizeof(float), stream);
    ksum_kernel<<<dim3(10, 128), dim3(256), 0, stream>>>(k, ksum);
    // 16*4096*32 units / 256 = 8192 blocks
    attn_kernel<<<dim3(8192), dim3(256), 0, stream>>>(q, v, ksum, out);
}